// Round 16
// baseline (75.500 us; speedup 1.0000x reference)
//
#include <hip/hip_runtime.h>
#include <stdint.h>

#define TPB 512          // threads per block (8 waves)
#define NBLK 512         // grid blocks; 2/CU co-resident by construction
#define CHUNK 128        // elements per sampled chunk (one per wave)
#define NSAMP (NBLK * 8) // 4096 sampled chunks -> same 1/16 coverage as R13/R15

// ---- u32 barrier area (memset-zeroed each call; 128B-padded slots) ----
#define U_C1A(g)  ((g) * 32)            // barrier A level-1 counters (64)
#define U_CMA     2048                  // barrier A master
#define U_F1(g)   (2080 + (g) * 32)     // barrier A flags (64)
#define U_C1B(g)  (4160 + (g) * 32)     // barrier B level-1
#define U_CMB     6208                  // barrier B master
#define U_F2(g)   (6240 + (g) * 32)     // barrier B flags (64)
#define U_C1C(g)  (8320 + (g) * 32)     // barrier C level-1
#define U_CMC     10368                 // barrier C master
#define U_ZERO_BYTES 41600              // 10400 u32

// ---- float offsets ----
#define OFF_MM     16384   // 2*NBLK minmax partials
#define OFF_GMM    17440   // 2 floats global {min,max}
#define OFF_TOP    17472   // 32 floats top-8 params (8 x float4)
#define OFF_TOPK   17504   // 8 u32 (index in u32 units)
#define OFF_NMIN8  17512
#define OFF_NMAX8  17520
#define OFF_PSC    20480   // NBLK*128 presel partials, block-major
#define OFF_RPART  90112   // NBLK*8 rescore partials

// exact reference fp32 order — identical everywhere params are derived
__device__ __forceinline__ float4 cand_params(int k, float xmin, float xmax,
                                              float* nmin_out, float* nmax_out) {
    float xrange = xmax - xmin;
    int ii = k >> 4;
    float zpf = (float)(k & 15);
    float tmp_max = xrange / 8.0f * (float)(ii + 1);
    float tmp_delta = tmp_max / 15.0f;
    float shift = zpf * tmp_delta;
    float new_min = fmaxf(0.0f - shift, xmin);
    float new_max = fminf(tmp_max - shift, xmax);
    float min_neg = fminf(new_min, 0.0f);
    float max_pos = fmaxf(new_max, 0.0f);
    float scale = fmaxf((max_pos - min_neg) / 15.0f, 1e-8f);
    float zp = 0.0f - rintf(min_neg / scale);
    zp = fminf(fmaxf(zp, 0.0f), 15.0f);
    float4 p;
    p.x = 1.0f / scale;
    p.y = scale;
    p.z = 0.0f - zp;
    p.w = 15.0f - zp;
    *nmin_out = new_min;
    *nmax_out = new_max;
    return p;
}

#define QUANT1(xv) { \
    float t0_ = (xv) * p0.x; float r0_ = rintf(t0_); \
    float c0_ = __builtin_amdgcn_fmed3f(r0_, p0.z, p0.w); \
    float d0_ = __builtin_fmaf(c0_, p0.y, -(xv)); \
    a0 = __builtin_fmaf(d0_, d0_, a0); \
    float t1_ = (xv) * p1.x; float r1_ = rintf(t1_); \
    float c1_ = __builtin_amdgcn_fmed3f(r1_, p1.z, p1.w); \
    float d1_ = __builtin_fmaf(c1_, p1.y, -(xv)); \
    a1 = __builtin_fmaf(d1_, d1_, a1); }
#define QUANT4(V) { QUANT1(V.x) QUANT1(V.y) QUANT1(V.z) QUANT1(V.w) }

#define RQc(xv, qc, acc) { \
    float t_ = (xv) * qc.x; float r_ = rintf(t_); \
    float c_ = __builtin_amdgcn_fmed3f(r_, qc.z, qc.w); \
    float d_ = __builtin_fmaf(c_, qc.y, -(xv)); \
    acc = __builtin_fmaf(d_, d_, acc); }
#define RQ8(xv) { RQc(xv,q0,b0) RQc(xv,q1,b1) RQc(xv,q2,b2) RQc(xv,q3,b3) \
                  RQc(xv,q4,b4) RQc(xv,q5,b5) RQc(xv,q6,b6) RQc(xv,q7,b7) }

// relaxed agent-scope atomics: coherence-point path, NO cache flush ops
#define ALOADF(p)    __hip_atomic_load((p), __ATOMIC_RELAXED, __HIP_MEMORY_SCOPE_AGENT)
#define ASTOREF(p,v) __hip_atomic_store((p), (v), __ATOMIC_RELAXED, __HIP_MEMORY_SCOPE_AGENT)
#define ALOADU(p)    __hip_atomic_load((p), __ATOMIC_RELAXED, __HIP_MEMORY_SCOPE_AGENT)
#define ASTOREU(p,v) __hip_atomic_store((p), (v), __ATOMIC_RELAXED, __HIP_MEMORY_SCOPE_AGENT)
#define AFADDU(p)    __hip_atomic_fetch_add((p), 1u, __ATOMIC_RELAXED, __HIP_MEMORY_SCOPE_AGENT)
#define VMDRAIN()    asm volatile("s_waitcnt vmcnt(0)" ::: "memory")

// two-level arrival: returns 1 in *tailOut (shared) for exactly one block
#define ARRIVE(C1_MACRO, CM_OFF) { \
    if (tid == 0) { \
        int tail_ = 0; \
        uint32_t old_ = AFADDU(&U[C1_MACRO(blk & 63)]); \
        if (old_ == 7) { \
            uint32_t m_ = AFADDU(&U[CM_OFF]); \
            tail_ = (m_ == 63); \
        } \
        lastF = tail_; \
    } \
    __syncthreads(); }

// Single fused kernel. Co-residency: launch_bounds(512,4) caps VGPR at 128
// (body ~60), LDS ~14KB -> >=2 blocks/CU x 256 CU = all 512 blocks resident
// (verified live in R14/R15 at this exact config), so spin barriers are safe.
__global__ __launch_bounds__(TPB, 4) void k_all(const float* __restrict__ x, int n,
                                                float* __restrict__ W,
                                                float* __restrict__ out,
                                                int nwc, int gstride) {
    __shared__ float ls[8][CHUNK];       // 4 KB presel staging (wave-private)
    __shared__ float wsum[8][128];       // 4 KB
    __shared__ float smn[8], smx[8];
    __shared__ float sjs[128][4];
    __shared__ unsigned long long keys[128];
    __shared__ unsigned long long lmin[8];
    __shared__ int sel[8];
    __shared__ float red8[8][64];
    __shared__ float Sc[8];
    __shared__ float sp[32];
    __shared__ float gmm[2];
    __shared__ int lastF;

    uint32_t* U = (uint32_t*)W;
    int tid = threadIdx.x, lane = tid & 63;
    int wv = __builtin_amdgcn_readfirstlane(tid >> 6);
    int blk = blockIdx.x;
    long nl = (long)n;
    float* mm = W + OFF_MM;

    // ================= Phase 0: minmax =================
    {
        int n4 = n >> 2;
        const float4* x4 = (const float4*)x;
        float mn = INFINITY, mx = -INFINITY;
        int idx = blk * TPB + tid;
        int stride = NBLK * TPB;
        for (int i = idx; i < n4; i += stride) {
            float4 v = x4[i];
            mn = fminf(mn, fminf(fminf(v.x, v.y), fminf(v.z, v.w)));
            mx = fmaxf(mx, fmaxf(fmaxf(v.x, v.y), fmaxf(v.z, v.w)));
        }
        for (int i = (n4 << 2) + idx; i < n; i += stride) {
            float v = x[i];
            mn = fminf(mn, v);
            mx = fmaxf(mx, v);
        }
        #pragma unroll
        for (int m = 32; m; m >>= 1) {
            mn = fminf(mn, __shfl_xor(mn, m, 64));
            mx = fmaxf(mx, __shfl_xor(mx, m, 64));
        }
        if (lane == 0) { smn[wv] = mn; smx[wv] = mx; }
        __syncthreads();
        if (tid == 0) {
            float a = smn[0], b = smx[0];
            #pragma unroll
            for (int w = 1; w < 8; ++w) { a = fminf(a, smn[w]); b = fmaxf(b, smx[w]); }
            ASTOREF(&mm[2 * blk + 0], a);
            ASTOREF(&mm[2 * blk + 1], b);
        }
    }
    VMDRAIN();
    __syncthreads();
    ARRIVE(U_C1A, U_CMA)
    if (lastF) {
        // tail: reduce 512 pairs (one per thread; order-free fmin/fmax)
        float mn2 = ALOADF(&mm[2 * tid + 0]);
        float mx2 = ALOADF(&mm[2 * tid + 1]);
        #pragma unroll
        for (int m = 32; m; m >>= 1) {
            mn2 = fminf(mn2, __shfl_xor(mn2, m, 64));
            mx2 = fmaxf(mx2, __shfl_xor(mx2, m, 64));
        }
        if (lane == 0) { smn[wv] = mn2; smx[wv] = mx2; }
        __syncthreads();
        if (tid == 0) {
            float a = smn[0], b = smx[0];
            #pragma unroll
            for (int w = 1; w < 8; ++w) { a = fminf(a, smn[w]); b = fmaxf(b, smx[w]); }
            ASTOREF(&W[OFF_GMM + 0], a);
            ASTOREF(&W[OFF_GMM + 1], b);
            VMDRAIN();
        }
        __syncthreads();
        if (tid < 64) ASTOREU(&U[U_F1(tid)], 1u);   // distributed release
    } else {
        if (tid == 0) {
            while (ALOADU(&U[U_F1(blk & 63)]) == 0u) __builtin_amdgcn_s_sleep(8);
        }
        __syncthreads();
    }
    if (tid < 2) gmm[tid] = ALOADF(&W[OFF_GMM + tid]);
    __syncthreads();
    float xmin = gmm[0], xmax = gmm[1];
    float dum0, dum1;
    float4 p0 = cand_params(2 * lane + 0, xmin, xmax, &dum0, &dum1);
    float4 p1 = cand_params(2 * lane + 1, xmin, xmax, &dum0, &dum1);

    // ================= Phase 1: balanced presel (all blocks) =================
    {
        float a0 = 0.0f, a1 = 0.0f;
        long g = (long)(blk * 8 + wv) * gstride;    // one 128-elem chunk per wave
        if (g < (long)nwc) {
            long base = g * CHUNK;
            long e = base + (long)lane * 2;
            float2 v;
            if (base + CHUNK <= nl) {
                v = *(const float2*)(x + e);
            } else {
                v.x = (e + 0 < nl) ? x[e + 0] : 0.0f;   // pad scores 0 everywhere
                v.y = (e + 1 < nl) ? x[e + 1] : 0.0f;
            }
            *(float2*)(&ls[wv][lane * 2]) = v;
            asm volatile("s_waitcnt lgkmcnt(0)" ::: "memory");  // wave-private region
            __builtin_amdgcn_sched_barrier(0);
            const float4* l4 = (const float4*)(&ls[wv][0]);
            #pragma unroll 4
            for (int i = 0; i < CHUNK / 4; ++i) {
                float4 u = l4[i];
                QUANT4(u)
            }
        }
        wsum[wv][2 * lane + 0] = a0;
        wsum[wv][2 * lane + 1] = a1;
        __syncthreads();
        if (tid < 128) {
            float s = ((wsum[0][tid] + wsum[1][tid]) + (wsum[2][tid] + wsum[3][tid]))
                    + ((wsum[4][tid] + wsum[5][tid]) + (wsum[6][tid] + wsum[7][tid]));
            ASTOREF(&W[OFF_PSC + blk * 128 + tid], s);
        }
    }
    VMDRAIN();
    __syncthreads();
    ARRIVE(U_C1B, U_CMB)
    if (lastF) {
        // tail: 4-slice fixed-order reduce (depth 128) + top-8 lex-min + publish
        {
            int k = tid & 127, j = tid >> 7;        // j = 0..3
            const float* p = W + OFF_PSC;
            float s = 0.0f;
            for (int b = j * (NBLK / 4); b < (j + 1) * (NBLK / 4); ++b)
                s += ALOADF(&p[b * 128 + k]);       // fixed order per slice
            sjs[k][j] = s;
        }
        __syncthreads();
        if (tid < 128) {
            float sc = (sjs[tid][0] + sjs[tid][1]) + (sjs[tid][2] + sjs[tid][3]);
            uint32_t tb = __float_as_uint(sc);
            tb = (tb & 0x80000000u) ? ~tb : (tb | 0x80000000u);  // order-preserving
            keys[tid] = (((unsigned long long)tb) << 32) | (unsigned)tid;
        }
        __syncthreads();
        for (int r = 0; r < 8; ++r) {
            unsigned long long kk = (tid < 128) ? keys[tid] : ~0ull;
            #pragma unroll
            for (int m = 32; m; m >>= 1) {
                unsigned long long o = __shfl_xor(kk, m, 64);
                kk = (o < kk) ? o : kk;
            }
            if (lane == 0) lmin[wv] = kk;
            __syncthreads();
            if (tid == 0) {
                unsigned long long g2 = lmin[0];
                if (lmin[1] < g2) g2 = lmin[1];
                int kid = (int)(g2 & 0x7fu);
                sel[r] = kid;
                keys[kid] = ~0ull;
            }
            __syncthreads();
        }
        if (tid < 8) {
            int kid = sel[tid];
            float nmi, nma;
            float4 p = cand_params(kid, xmin, xmax, &nmi, &nma);
            ASTOREF(&W[OFF_TOP + 4 * tid + 0], p.x);
            ASTOREF(&W[OFF_TOP + 4 * tid + 1], p.y);
            ASTOREF(&W[OFF_TOP + 4 * tid + 2], p.z);
            ASTOREF(&W[OFF_TOP + 4 * tid + 3], p.w);
            ASTOREU(&U[OFF_TOPK + tid], (uint32_t)kid);
            ASTOREF(&W[OFF_NMIN8 + tid], nmi);
            ASTOREF(&W[OFF_NMAX8 + tid], nma);
        }
        VMDRAIN();
        __syncthreads();
        if (tid < 64) ASTOREU(&U[U_F2(tid)], 1u);
    } else {
        if (tid == 0) {
            while (ALOADU(&U[U_F2(blk & 63)]) == 0u) __builtin_amdgcn_s_sleep(8);
        }
        __syncthreads();
    }
    if (tid < 32) sp[tid] = ALOADF(&W[OFF_TOP + tid]);
    __syncthreads();

    // ================= Phase 2: exact rescore of 8 finalists =================
    {
        float4 q0 = make_float4(sp[0],  sp[1],  sp[2],  sp[3]);
        float4 q1 = make_float4(sp[4],  sp[5],  sp[6],  sp[7]);
        float4 q2 = make_float4(sp[8],  sp[9],  sp[10], sp[11]);
        float4 q3 = make_float4(sp[12], sp[13], sp[14], sp[15]);
        float4 q4 = make_float4(sp[16], sp[17], sp[18], sp[19]);
        float4 q5 = make_float4(sp[20], sp[21], sp[22], sp[23]);
        float4 q6 = make_float4(sp[24], sp[25], sp[26], sp[27]);
        float4 q7 = make_float4(sp[28], sp[29], sp[30], sp[31]);
        float b0 = 0, b1 = 0, b2 = 0, b3 = 0, b4 = 0, b5 = 0, b6 = 0, b7 = 0;
        int n4 = n >> 2;
        const float4* x4 = (const float4*)x;
        int gtid = blk * TPB + tid;
        int stride = NBLK * TPB;
        for (int i = gtid; i < n4; i += stride) {
            float4 v = x4[i];
            RQ8(v.x) RQ8(v.y) RQ8(v.z) RQ8(v.w)
        }
        for (int i = (n4 << 2) + gtid; i < n; i += stride) {
            float xv = x[i];
            RQ8(xv)
        }
        #pragma unroll
        for (int m = 32; m; m >>= 1) {
            b0 += __shfl_xor(b0, m, 64); b1 += __shfl_xor(b1, m, 64);
            b2 += __shfl_xor(b2, m, 64); b3 += __shfl_xor(b3, m, 64);
            b4 += __shfl_xor(b4, m, 64); b5 += __shfl_xor(b5, m, 64);
            b6 += __shfl_xor(b6, m, 64); b7 += __shfl_xor(b7, m, 64);
        }
        if (lane == 0) {
            wsum[wv][0] = b0; wsum[wv][1] = b1; wsum[wv][2] = b2; wsum[wv][3] = b3;
            wsum[wv][4] = b4; wsum[wv][5] = b5; wsum[wv][6] = b6; wsum[wv][7] = b7;
        }
        __syncthreads();
        if (tid < 8) {
            float s = ((wsum[0][tid] + wsum[1][tid]) + (wsum[2][tid] + wsum[3][tid]))
                    + ((wsum[4][tid] + wsum[5][tid]) + (wsum[6][tid] + wsum[7][tid]));
            ASTOREF(&W[OFF_RPART + blk * 8 + tid], s);
        }
    }
    VMDRAIN();
    __syncthreads();
    ARRIVE(U_C1C, U_CMC)
    if (!lastF) return;

    // final tail: 64-slice fixed-order reduce (depth 8) + lex (S,k) argmin
    {
        int c = tid >> 6, j = tid & 63;
        float s = 0.0f;
        for (int b = j; b < NBLK; b += 64) s += ALOADF(&W[OFF_RPART + b * 8 + c]);
        red8[c][j] = s;
    }
    __syncthreads();
    if (lane == 0) {
        int c = wv;
        float t = 0.0f;
        for (int jj = 0; jj < 64; ++jj) t += red8[c][jj];   // fixed order
        Sc[c] = t;
    }
    __syncthreads();
    if (tid == 0) {
        float bs = Sc[0];
        uint32_t bk = ALOADU(&U[OFF_TOPK + 0]);
        int br = 0;
        for (int cc = 1; cc < 8; ++cc) {
            uint32_t kc = ALOADU(&U[OFF_TOPK + cc]);
            if (Sc[cc] < bs || (Sc[cc] == bs && kc < bk)) { bs = Sc[cc]; bk = kc; br = cc; }
        }
        out[0] = ALOADF(&W[OFF_NMIN8 + br]);
        out[1] = ALOADF(&W[OFF_NMAX8 + br]);
    }
}

extern "C" void kernel_launch(void* const* d_in, const int* in_sizes, int n_in,
                              void* d_out, int out_size, void* d_ws, size_t ws_size,
                              hipStream_t stream) {
    const float* x = (const float*)d_in[0];
    int n = in_sizes[0];
    float* out = (float*)d_out;
    float* W = (float*)d_ws;

    int nwc = (n + CHUNK - 1) / CHUNK;
    int gstride = nwc / NSAMP;
    if (gstride < 1) gstride = 1;

    hipMemsetAsync(W, 0, U_ZERO_BYTES, stream);   // zero barrier state (graph-capturable)
    k_all<<<NBLK, TPB, 0, stream>>>(x, n, W, out, nwc, gstride);
}

// Round 17
// 42.321 us; speedup vs baseline: 1.7840x; 1.7840x over previous
//
#include <hip/hip_runtime.h>
#include <stdint.h>

#define TPB 512          // threads per block (8 waves)
#define NBLK 512         // grid blocks; >=2/CU resident by construction
#define SBLK 256         // sampling blocks (256*8 waves = 2048 chunks, same set as R13)
#define CHUNK 256
#define NSAMP (SBLK * 8)

// ---- u32 barrier area (zeroed by K1 block 0 every call) ----
#define U_C1(g)   ((g) * 32)            // 64 level-1 counters, 128 B apart
#define U_CM      2048                  // master counter (barrier 1)
#define U_FLAG(g) (4096 + (g) * 32)     // 64 flag copies, 128 B apart
#define U_C1B(g)  (8192 + (g) * 32)     // level-1 counters (barrier 2)
#define U_CMB     10240                 // master counter (barrier 2)
#define U_ZERO_N  12288                 // u32 count zeroed by K1

// ---- float offsets ----
#define OFF_MM     16384   // 2*NBLK minmax partials
#define OFF_TOP    17408   // 32 floats: top-8 params (8 x float4)
#define OFF_TOPK   17440   // 8 u32 (as u32 index into W)
#define OFF_NMIN8  17448
#define OFF_NMAX8  17456
#define OFF_PSC    20480   // SBLK*128 presel partials, block-major
#define OFF_RPART  53248   // NBLK*8 rescore partials

// exact reference fp32 order — identical everywhere params are derived
__device__ __forceinline__ float4 cand_params(int k, float xmin, float xmax,
                                              float* nmin_out, float* nmax_out) {
    float xrange = xmax - xmin;
    int ii = k >> 4;
    float zpf = (float)(k & 15);
    float tmp_max = xrange / 8.0f * (float)(ii + 1);
    float tmp_delta = tmp_max / 15.0f;
    float shift = zpf * tmp_delta;
    float new_min = fmaxf(0.0f - shift, xmin);
    float new_max = fminf(tmp_max - shift, xmax);
    float min_neg = fminf(new_min, 0.0f);
    float max_pos = fmaxf(new_max, 0.0f);
    float scale = fmaxf((max_pos - min_neg) / 15.0f, 1e-8f);
    float zp = 0.0f - rintf(min_neg / scale);
    zp = fminf(fmaxf(zp, 0.0f), 15.0f);
    float4 p;
    p.x = 1.0f / scale;
    p.y = scale;
    p.z = 0.0f - zp;
    p.w = 15.0f - zp;
    *nmin_out = new_min;
    *nmax_out = new_max;
    return p;
}

#define QUANT1(xv) { \
    float t0_ = (xv) * p0.x; float r0_ = rintf(t0_); \
    float c0_ = __builtin_amdgcn_fmed3f(r0_, p0.z, p0.w); \
    float d0_ = __builtin_fmaf(c0_, p0.y, -(xv)); \
    a0 = __builtin_fmaf(d0_, d0_, a0); \
    float t1_ = (xv) * p1.x; float r1_ = rintf(t1_); \
    float c1_ = __builtin_amdgcn_fmed3f(r1_, p1.z, p1.w); \
    float d1_ = __builtin_fmaf(c1_, p1.y, -(xv)); \
    a1 = __builtin_fmaf(d1_, d1_, a1); }
#define QUANT4(V) { QUANT1(V.x) QUANT1(V.y) QUANT1(V.z) QUANT1(V.w) }

#define RQc(xv, qc, acc) { \
    float t_ = (xv) * qc.x; float r_ = rintf(t_); \
    float c_ = __builtin_amdgcn_fmed3f(r_, qc.z, qc.w); \
    float d_ = __builtin_fmaf(c_, qc.y, -(xv)); \
    acc = __builtin_fmaf(d_, d_, acc); }
#define RQ8(xv) { RQc(xv,q0,b0) RQc(xv,q1,b1) RQc(xv,q2,b2) RQc(xv,q3,b3) \
                  RQc(xv,q4,b4) RQc(xv,q5,b5) RQc(xv,q6,b6) RQc(xv,q7,b7) }

// relaxed agent-scope atomics: coherence-point path, NO cache flush ops
#define ALOADF(p)    __hip_atomic_load((p), __ATOMIC_RELAXED, __HIP_MEMORY_SCOPE_AGENT)
#define ASTOREF(p,v) __hip_atomic_store((p), (v), __ATOMIC_RELAXED, __HIP_MEMORY_SCOPE_AGENT)
#define ALOADU(p)    __hip_atomic_load((p), __ATOMIC_RELAXED, __HIP_MEMORY_SCOPE_AGENT)
#define ASTOREU(p,v) __hip_atomic_store((p), (v), __ATOMIC_RELAXED, __HIP_MEMORY_SCOPE_AGENT)
#define AFADDU(p)    __hip_atomic_fetch_add((p), 1u, __ATOMIC_RELAXED, __HIP_MEMORY_SCOPE_AGENT)
#define VMDRAIN()    asm volatile("s_waitcnt vmcnt(0)" ::: "memory")

// ---- kernel 1: minmax partials + zero barrier area ----
__global__ __launch_bounds__(TPB) void k_minmax(const float* __restrict__ x, int n,
                                                float* __restrict__ W) {
    uint32_t* U = (uint32_t*)W;
    if (blockIdx.x == 0) {
        for (int i = threadIdx.x; i < U_ZERO_N; i += TPB) U[i] = 0u;
    }
    float* mm = W + OFF_MM;
    int n4 = n >> 2;
    const float4* x4 = (const float4*)x;
    float mn = INFINITY, mx = -INFINITY;
    int idx = blockIdx.x * TPB + threadIdx.x;
    int stride = gridDim.x * TPB;
    for (int i = idx; i < n4; i += stride) {
        float4 v = x4[i];
        mn = fminf(mn, fminf(fminf(v.x, v.y), fminf(v.z, v.w)));
        mx = fmaxf(mx, fmaxf(fmaxf(v.x, v.y), fmaxf(v.z, v.w)));
    }
    for (int i = (n4 << 2) + idx; i < n; i += stride) {
        float v = x[i];
        mn = fminf(mn, v);
        mx = fmaxf(mx, v);
    }
    #pragma unroll
    for (int m = 32; m; m >>= 1) {
        mn = fminf(mn, __shfl_xor(mn, m, 64));
        mx = fmaxf(mx, __shfl_xor(mx, m, 64));
    }
    __shared__ float smn[8], smx[8];
    int wv = threadIdx.x >> 6;
    if ((threadIdx.x & 63) == 0) { smn[wv] = mn; smx[wv] = mx; }
    __syncthreads();
    if (threadIdx.x == 0) {
        float a = smn[0], b = smx[0];
        #pragma unroll
        for (int w = 1; w < 8; ++w) { a = fminf(a, smn[w]); b = fmaxf(b, smx[w]); }
        mm[2 * blockIdx.x + 0] = a;
        mm[2 * blockIdx.x + 1] = b;
    }
}

// ---- kernel 2: presel + internal low-contention barrier + rescore ----
__global__ __launch_bounds__(TPB, 4) void k_main(const float* __restrict__ x, int n,
                                                 float* __restrict__ W,
                                                 float* __restrict__ out,
                                                 int nwc, int gstride) {
    __shared__ float ls[8][CHUNK];       // 8 KB presel staging (wave-private)
    __shared__ float wsum[8][128];       // 4 KB (presel sums; reused in rescore)
    __shared__ float smn[8], smx[8];
    __shared__ float sjs[128][4];
    __shared__ unsigned long long keys[128];
    __shared__ unsigned long long lmin[8];
    __shared__ int sel[8];
    __shared__ float red8[8][64];
    __shared__ float Sc[8];
    __shared__ float sp[32];
    __shared__ int lastF;

    uint32_t* U = (uint32_t*)W;
    int tid = threadIdx.x, lane = tid & 63;
    int wv = __builtin_amdgcn_readfirstlane(tid >> 6);
    int blk = blockIdx.x;
    long nl = (long)n;
    const float* mm = W + OFF_MM;

    // per-block exact global minmax from K1 partials (plain cached loads)
    {
        float mn = mm[2 * tid + 0];       // NBLK==TPB: one pair per thread
        float mx = mm[2 * tid + 1];
        #pragma unroll
        for (int m = 32; m; m >>= 1) {
            mn = fminf(mn, __shfl_xor(mn, m, 64));
            mx = fmaxf(mx, __shfl_xor(mx, m, 64));
        }
        if (lane == 0) { smn[wv] = mn; smx[wv] = mx; }
    }
    __syncthreads();
    float xmin = smn[0], xmax = smx[0];
    #pragma unroll
    for (int w = 1; w < 8; ++w) {
        xmin = fminf(xmin, smn[w]);
        xmax = fmaxf(xmax, smx[w]);
    }
    float dum0, dum1;
    float4 p0 = cand_params(2 * lane + 0, xmin, xmax, &dum0, &dum1);
    float4 p1 = cand_params(2 * lane + 1, xmin, xmax, &dum0, &dum1);

    // ---------- presel sample (blocks 0..SBLK-1), same chunk set as R13 ----------
    {
        float a0 = 0.0f, a1 = 0.0f;
        if (blk < SBLK) {
            long g = (long)(blk * 8 + wv) * gstride;
            if (g < (long)nwc) {
                long base = g * CHUNK;
                long e = base + (long)lane * 4;
                float4 v;
                if (base + CHUNK <= nl) {
                    v = *(const float4*)(x + e);
                } else {
                    v.x = (e + 0 < nl) ? x[e + 0] : 0.0f;   // pad scores 0 everywhere
                    v.y = (e + 1 < nl) ? x[e + 1] : 0.0f;
                    v.z = (e + 2 < nl) ? x[e + 2] : 0.0f;
                    v.w = (e + 3 < nl) ? x[e + 3] : 0.0f;
                }
                *(float4*)(&ls[wv][lane * 4]) = v;
                asm volatile("s_waitcnt lgkmcnt(0)" ::: "memory");  // wave-private region
                __builtin_amdgcn_sched_barrier(0);
                const float4* l4 = (const float4*)(&ls[wv][0]);
                #pragma unroll 4
                for (int i = 0; i < CHUNK / 4; ++i) {
                    float4 u = l4[i];
                    QUANT4(u)
                }
            }
            wsum[wv][2 * lane + 0] = a0;
            wsum[wv][2 * lane + 1] = a1;
            __syncthreads();
            if (tid < 128) {
                float s = ((wsum[0][tid] + wsum[1][tid]) + (wsum[2][tid] + wsum[3][tid]))
                        + ((wsum[4][tid] + wsum[5][tid]) + (wsum[6][tid] + wsum[7][tid]));
                ASTOREF(&W[OFF_PSC + blk * 128 + tid], s);
            }
        }
    }
    VMDRAIN();           // per-wave: partial stores acked at coherence point
    __syncthreads();

    // ---------- barrier 1: two-level arrival tree + distributed flags ----------
    if (tid == 0) {
        int tail = 0;
        uint32_t old = AFADDU(&U[U_C1(blk & 63)]);   // 8 blocks per level-1 counter
        if (old == 7) {
            uint32_t m = AFADDU(&U[U_CM]);           // 64 master arrivals
            tail = (m == 63);
        }
        lastF = tail;
    }
    __syncthreads();
    if (lastF) {
        // tail: fixed-order presel reduce, ILP-4 (4 independent load chains per
        // thread, deterministic combine), then top-8 lex-min, publish.
        {
            int k = tid & 127, j = tid >> 7;         // j = 0..3, 64 blocks per slice
            const float* p = W + OFF_PSC;
            float s0 = 0, s1 = 0, s2 = 0, s3 = 0;
            int bb = j * (SBLK / 4);
            for (int b = bb; b < bb + (SBLK / 4); b += 4) {
                s0 += ALOADF(&p[(b + 0) * 128 + k]);
                s1 += ALOADF(&p[(b + 1) * 128 + k]);
                s2 += ALOADF(&p[(b + 2) * 128 + k]);
                s3 += ALOADF(&p[(b + 3) * 128 + k]);
            }
            sjs[k][j] = (s0 + s1) + (s2 + s3);       // fixed order
        }
        __syncthreads();
        if (tid < 128) {
            float sc = (sjs[tid][0] + sjs[tid][1]) + (sjs[tid][2] + sjs[tid][3]);
            uint32_t tb = __float_as_uint(sc);
            tb = (tb & 0x80000000u) ? ~tb : (tb | 0x80000000u);   // order-preserving
            keys[tid] = (((unsigned long long)tb) << 32) | (unsigned)tid;
        }
        __syncthreads();
        for (int r = 0; r < 8; ++r) {
            unsigned long long kk = (tid < 128) ? keys[tid] : ~0ull;
            #pragma unroll
            for (int m = 32; m; m >>= 1) {
                unsigned long long o = __shfl_xor(kk, m, 64);
                kk = (o < kk) ? o : kk;
            }
            if (lane == 0) lmin[wv] = kk;
            __syncthreads();
            if (tid == 0) {
                unsigned long long g2 = lmin[0];
                if (lmin[1] < g2) g2 = lmin[1];
                int kid = (int)(g2 & 0x7fu);
                sel[r] = kid;
                keys[kid] = ~0ull;
            }
            __syncthreads();
        }
        if (tid < 8) {
            int kid = sel[tid];
            float nmi, nma;
            float4 p = cand_params(kid, xmin, xmax, &nmi, &nma);
            ASTOREF(&W[OFF_TOP + 4 * tid + 0], p.x);
            ASTOREF(&W[OFF_TOP + 4 * tid + 1], p.y);
            ASTOREF(&W[OFF_TOP + 4 * tid + 2], p.z);
            ASTOREF(&W[OFF_TOP + 4 * tid + 3], p.w);
            ASTOREU(&U[OFF_TOPK + tid], (uint32_t)kid);
            ASTOREF(&W[OFF_NMIN8 + tid], nmi);
            ASTOREF(&W[OFF_NMAX8 + tid], nma);
        }
        VMDRAIN();                     // data visible before any flag
        __syncthreads();
        if (tid < 64) ASTOREU(&U[U_FLAG(tid)], 1u);   // 64 distributed flag copies
    } else {
        if (tid == 0) {
            // <=8 pollers per flag address, short sleep backoff: no LLC convoy
            while (ALOADU(&U[U_FLAG(blk & 63)]) == 0u) __builtin_amdgcn_s_sleep(4);
        }
        __syncthreads();
    }

    if (tid < 32) sp[tid] = ALOADF(&W[OFF_TOP + tid]);
    __syncthreads();

    // ---------- exact rescore of 8 finalists ----------
    {
        float4 q0 = make_float4(sp[0],  sp[1],  sp[2],  sp[3]);
        float4 q1 = make_float4(sp[4],  sp[5],  sp[6],  sp[7]);
        float4 q2 = make_float4(sp[8],  sp[9],  sp[10], sp[11]);
        float4 q3 = make_float4(sp[12], sp[13], sp[14], sp[15]);
        float4 q4 = make_float4(sp[16], sp[17], sp[18], sp[19]);
        float4 q5 = make_float4(sp[20], sp[21], sp[22], sp[23]);
        float4 q6 = make_float4(sp[24], sp[25], sp[26], sp[27]);
        float4 q7 = make_float4(sp[28], sp[29], sp[30], sp[31]);
        float b0 = 0, b1 = 0, b2 = 0, b3 = 0, b4 = 0, b5 = 0, b6 = 0, b7 = 0;
        int n4 = n >> 2;
        const float4* x4 = (const float4*)x;
        int gtid = blk * TPB + tid;
        int stride = NBLK * TPB;
        for (int i = gtid; i < n4; i += stride) {
            float4 v = x4[i];
            RQ8(v.x) RQ8(v.y) RQ8(v.z) RQ8(v.w)
        }
        for (int i = (n4 << 2) + gtid; i < n; i += stride) {
            float xv = x[i];
            RQ8(xv)
        }
        #pragma unroll
        for (int m = 32; m; m >>= 1) {
            b0 += __shfl_xor(b0, m, 64); b1 += __shfl_xor(b1, m, 64);
            b2 += __shfl_xor(b2, m, 64); b3 += __shfl_xor(b3, m, 64);
            b4 += __shfl_xor(b4, m, 64); b5 += __shfl_xor(b5, m, 64);
            b6 += __shfl_xor(b6, m, 64); b7 += __shfl_xor(b7, m, 64);
        }
        if (lane == 0) {
            wsum[wv][0] = b0; wsum[wv][1] = b1; wsum[wv][2] = b2; wsum[wv][3] = b3;
            wsum[wv][4] = b4; wsum[wv][5] = b5; wsum[wv][6] = b6; wsum[wv][7] = b7;
        }
        __syncthreads();
        if (tid < 8) {
            float s = ((wsum[0][tid] + wsum[1][tid]) + (wsum[2][tid] + wsum[3][tid]))
                    + ((wsum[4][tid] + wsum[5][tid]) + (wsum[6][tid] + wsum[7][tid]));
            ASTOREF(&W[OFF_RPART + blk * 8 + tid], s);
        }
    }
    VMDRAIN();
    __syncthreads();

    // ---------- barrier 2: arrive-and-exit (no spin) ----------
    if (tid == 0) {
        int tail = 0;
        uint32_t old = AFADDU(&U[U_C1B(blk & 63)]);
        if (old == 7) {
            uint32_t m = AFADDU(&U[U_CMB]);
            tail = (m == 63);
        }
        lastF = tail;
    }
    __syncthreads();
    if (!lastF) return;

    // final tail: 64-slice fixed-order reduce (depth 8) + lex (S,k) argmin
    {
        int c = tid >> 6, j = tid & 63;
        float s = 0.0f;
        for (int b = j; b < NBLK; b += 64) s += ALOADF(&W[OFF_RPART + b * 8 + c]);
        red8[c][j] = s;
    }
    __syncthreads();
    if (lane == 0) {
        int c = wv;
        float t = 0.0f;
        for (int jj = 0; jj < 64; ++jj) t += red8[c][jj];   // fixed order
        Sc[c] = t;
    }
    __syncthreads();
    if (tid == 0) {
        float bs = Sc[0];
        uint32_t bk = ALOADU(&U[OFF_TOPK + 0]);
        int br = 0;
        for (int cc = 1; cc < 8; ++cc) {
            uint32_t kc = ALOADU(&U[OFF_TOPK + cc]);
            if (Sc[cc] < bs || (Sc[cc] == bs && kc < bk)) { bs = Sc[cc]; bk = kc; br = cc; }
        }
        out[0] = ALOADF(&W[OFF_NMIN8 + br]);
        out[1] = ALOADF(&W[OFF_NMAX8 + br]);
    }
}

extern "C" void kernel_launch(void* const* d_in, const int* in_sizes, int n_in,
                              void* d_out, int out_size, void* d_ws, size_t ws_size,
                              hipStream_t stream) {
    const float* x = (const float*)d_in[0];
    int n = in_sizes[0];
    float* out = (float*)d_out;
    float* W = (float*)d_ws;

    int nwc = (n + CHUNK - 1) / CHUNK;
    int gstride = nwc / NSAMP;
    if (gstride < 1) gstride = 1;

    k_minmax<<<NBLK, TPB, 0, stream>>>(x, n, W);
    k_main<<<NBLK, TPB, 0, stream>>>(x, n, W, out, nwc, gstride);
}